// Round 3
// baseline (1856.832 us; speedup 1.0000x reference)
//
#include <hip/hip_runtime.h>
#include <stdint.h>

#define Hh   51
#define G4   204      // 4*H
#define Bsz  1024
#define Tin  512
#define Ttot 576      // Tin + future(64)
#define NB   2        // batch elements per block

__device__ __forceinline__ float fast_sigmoid(float x) {
    return 1.0f / (1.0f + __expf(-x));
}
// tanh(x) = 2*sigmoid(2x) - 1

__global__ __launch_bounds__(256, 2)
void lstm_seq_kernel(const float* __restrict__ inp,    // [B, Tin]
                     const float* __restrict__ Wih1,   // [204, 1]
                     const float* __restrict__ Whh1,   // [204, 51]
                     const float* __restrict__ bih1,   // [204]
                     const float* __restrict__ bhh1,   // [204]
                     const float* __restrict__ Wih2,   // [204, 51]
                     const float* __restrict__ Whh2,   // [204, 51]
                     const float* __restrict__ bih2,   // [204]
                     const float* __restrict__ bhh2,   // [204]
                     const float* __restrict__ Wl,     // [1, 51]
                     const float* __restrict__ blp,    // [1]
                     float* __restrict__ outp)         // [B, Ttot]
{
    const int j  = threadIdx.x;          // gate-row index (0..203 active)
    const int b0 = blockIdx.x * NB;      // this block's two batch elements

    // hcat: [0..50]=h1, [51..101]=h2, [102..103]=0 pad (float4-aligned dots).
    // L1 dot covers 0..51 with w1[51]=0; L2 dot covers 0..103 with w2[102..103]=0.
    __shared__ float hcat[NB][104];
    __shared__ float gates[NB][G4];
    __shared__ float xnb[NB];

    if (j < 104) { hcat[0][j] = 0.f; hcat[1][j] = 0.f; }

    // ---- weights into registers (fp32), row clamped for inactive threads ----
    const int jr = (j < G4) ? j : (G4 - 1);
    float w1[52];    // Whh1 row, padded
    float w2[104];   // [Wih2 row | Whh2 row], padded
#pragma unroll
    for (int k = 0; k < Hh; ++k) w1[k] = Whh1[jr * Hh + k];
    w1[51] = 0.f;
#pragma unroll
    for (int k = 0; k < Hh; ++k) w2[k] = Wih2[jr * Hh + k];
#pragma unroll
    for (int k = 0; k < Hh; ++k) w2[Hh + k] = Whh2[jr * Hh + k];
    w2[102] = 0.f; w2[103] = 0.f;

    // Pin weights in VGPRs: asm outputs are non-rematerializable, so the
    // allocator cannot re-load them from global inside the t-loop (the round-2
    // kernel showed VGPR_Count=96 => compiler rematerialized 153 uncoalesced
    // global loads per step; that was the bottleneck).
#pragma unroll
    for (int k = 0; k < 52; ++k)  asm volatile("" : "+v"(w1[k]));
#pragma unroll
    for (int k = 0; k < 104; ++k) asm volatile("" : "+v"(w2[k]));

    float b1j   = bih1[jr] + bhh1[jr];
    float b2j   = bih2[jr] + bhh2[jr];
    float wih1j = Wih1[jr];
    const float wlj = (j < Hh) ? Wl[j] : 0.f;
    const float blv = blp[0];
    float c1a = 0.f, c1b = 0.f, c2a = 0.f, c2b = 0.f;

    float xa = inp[(size_t)b0 * Tin];
    float xb = inp[(size_t)(b0 + 1) * Tin];
    const bool tg = (j >= 2 * Hh) && (j < 3 * Hh);   // tanh gate rows

    __syncthreads();

    for (int t = 0; t < Ttot; ++t) {
        float x0 = (t < Tin) ? xa : xnb[0];
        float x1 = (t < Tin) ? xb : xnb[1];
        float xan = 0.f, xbn = 0.f;
        if (t + 1 < Tin) {                 // prefetch next step's inputs
            xan = inp[(size_t)b0 * Tin + t + 1];
            xbn = inp[(size_t)(b0 + 1) * Tin + t + 1];
        }

        // ---- P1: layer-1 gates for both batches (dot over h1, len 52) ----
        {
            float A0 = __builtin_fmaf(x0, wih1j, b1j), A1 = 0.f;
            float B0 = __builtin_fmaf(x1, wih1j, b1j), B1 = 0.f;
#pragma unroll
            for (int p = 0; p < 13; ++p) {
                float4 ha = *(const float4*)&hcat[0][4 * p];
                float4 hb = *(const float4*)&hcat[1][4 * p];
                A0 = __builtin_fmaf(w1[4 * p + 0], ha.x, A0);
                A1 = __builtin_fmaf(w1[4 * p + 1], ha.y, A1);
                A0 = __builtin_fmaf(w1[4 * p + 2], ha.z, A0);
                A1 = __builtin_fmaf(w1[4 * p + 3], ha.w, A1);
                B0 = __builtin_fmaf(w1[4 * p + 0], hb.x, B0);
                B1 = __builtin_fmaf(w1[4 * p + 1], hb.y, B1);
                B0 = __builtin_fmaf(w1[4 * p + 2], hb.z, B0);
                B1 = __builtin_fmaf(w1[4 * p + 3], hb.w, B1);
            }
            float aa = A0 + A1, ab = B0 + B1;
            float sa = fast_sigmoid(tg ? 2.f * aa : aa);
            float sb = fast_sigmoid(tg ? 2.f * ab : ab);
            if (j < G4) {
                gates[0][j] = tg ? (2.f * sa - 1.f) : sa;
                gates[1][j] = tg ? (2.f * sb - 1.f) : sb;
            }
        }
        __syncthreads();

        // ---- P2: layer-1 state ----
        if (j < Hh) {
            {
                float gi = gates[0][j],          gf = gates[0][Hh + j];
                float gg = gates[0][2 * Hh + j], go = gates[0][3 * Hh + j];
                c1a = __builtin_fmaf(gf, c1a, gi * gg);
                hcat[0][j] = go * (2.f * fast_sigmoid(2.f * c1a) - 1.f);
            }
            {
                float gi = gates[1][j],          gf = gates[1][Hh + j];
                float gg = gates[1][2 * Hh + j], go = gates[1][3 * Hh + j];
                c1b = __builtin_fmaf(gf, c1b, gi * gg);
                hcat[1][j] = go * (2.f * fast_sigmoid(2.f * c1b) - 1.f);
            }
        }
        __syncthreads();

        // ---- P3: layer-2 gates (dot over [h1;h2], len 104) ----
        {
            float A0 = b2j, A1 = 0.f, B0 = b2j, B1 = 0.f;
#pragma unroll
            for (int p = 0; p < 26; ++p) {
                float4 ha = *(const float4*)&hcat[0][4 * p];
                float4 hb = *(const float4*)&hcat[1][4 * p];
                A0 = __builtin_fmaf(w2[4 * p + 0], ha.x, A0);
                A1 = __builtin_fmaf(w2[4 * p + 1], ha.y, A1);
                A0 = __builtin_fmaf(w2[4 * p + 2], ha.z, A0);
                A1 = __builtin_fmaf(w2[4 * p + 3], ha.w, A1);
                B0 = __builtin_fmaf(w2[4 * p + 0], hb.x, B0);
                B1 = __builtin_fmaf(w2[4 * p + 1], hb.y, B1);
                B0 = __builtin_fmaf(w2[4 * p + 2], hb.z, B0);
                B1 = __builtin_fmaf(w2[4 * p + 3], hb.w, B1);
            }
            float aa = A0 + A1, ab = B0 + B1;
            float sa = fast_sigmoid(tg ? 2.f * aa : aa);
            float sb = fast_sigmoid(tg ? 2.f * ab : ab);
            if (j < G4) {
                gates[0][j] = tg ? (2.f * sa - 1.f) : sa;
                gates[1][j] = tg ? (2.f * sb - 1.f) : sb;
            }
        }
        __syncthreads();

        // ---- P4: layer-2 state + linear output (wave-0 shuffle reduce) ----
        float ca = 0.f, cb = 0.f;
        if (j < Hh) {
            {
                float gi = gates[0][j],          gf = gates[0][Hh + j];
                float gg = gates[0][2 * Hh + j], go = gates[0][3 * Hh + j];
                c2a = __builtin_fmaf(gf, c2a, gi * gg);
                float h2 = go * (2.f * fast_sigmoid(2.f * c2a) - 1.f);
                hcat[0][Hh + j] = h2;
                ca = wlj * h2;
            }
            {
                float gi = gates[1][j],          gf = gates[1][Hh + j];
                float gg = gates[1][2 * Hh + j], go = gates[1][3 * Hh + j];
                c2b = __builtin_fmaf(gf, c2b, gi * gg);
                float h2 = go * (2.f * fast_sigmoid(2.f * c2b) - 1.f);
                hcat[1][Hh + j] = h2;
                cb = wlj * h2;
            }
        }
        if (j < 64) {                        // first wave only
            float sa = ca, sb = cb;
#pragma unroll
            for (int m = 32; m >= 1; m >>= 1) {
                sa += __shfl_xor(sa, m, 64);
                sb += __shfl_xor(sb, m, 64);
            }
            if (j == 0) {
                float o0 = sa + blv, o1 = sb + blv;
                xnb[0] = o0; xnb[1] = o1;     // feedback for future phase
                outp[(size_t)b0 * Ttot + t]       = o0;
                outp[(size_t)(b0 + 1) * Ttot + t] = o1;
            }
        }
        __syncthreads();
        xa = xan; xb = xbn;
    }
}

extern "C" void kernel_launch(void* const* d_in, const int* in_sizes, int n_in,
                              void* d_out, int out_size, void* d_ws, size_t ws_size,
                              hipStream_t stream) {
    (void)in_sizes; (void)n_in; (void)out_size; (void)d_ws; (void)ws_size;
    lstm_seq_kernel<<<dim3(Bsz / NB), dim3(256), 0, stream>>>(
        (const float*)d_in[0], (const float*)d_in[1],
        (const float*)d_in[2], (const float*)d_in[3],
        (const float*)d_in[4], (const float*)d_in[5],
        (const float*)d_in[6], (const float*)d_in[7],
        (const float*)d_in[8], (const float*)d_in[9],
        (const float*)d_in[10], (float*)d_out);
}

// Round 4
// 1450.233 us; speedup vs baseline: 1.2804x; 1.2804x over previous
//
#include <hip/hip_runtime.h>
#include <stdint.h>

#define Hh   51
#define G4   204      // 4*H
#define Bsz  1024
#define Tin  512
#define Ttot 576      // Tin + future(64)
#define NB   2        // batch elements per block

typedef float v2f __attribute__((ext_vector_type(2)));

__device__ __forceinline__ float fast_sigmoid(float x) {
    return 1.0f / (1.0f + __expf(-x));
}
// tanh(x) = 2*sigmoid(2x) - 1

__device__ __forceinline__ v2f pk_fma(v2f a, v2f b, v2f c) {
#if __has_builtin(__builtin_elementwise_fma)
    return __builtin_elementwise_fma(a, b, c);   // -> v_pk_fma_f32
#else
    v2f r; r.x = __builtin_fmaf(a.x, b.x, c.x); r.y = __builtin_fmaf(a.y, b.y, c.y);
    return r;
#endif
}

__global__ __launch_bounds__(512, 4)
void lstm_seq_kernel(const float* __restrict__ inp,    // [B, Tin]
                     const float* __restrict__ Wih1,   // [204, 1]
                     const float* __restrict__ Whh1,   // [204, 51]
                     const float* __restrict__ bih1,   // [204]
                     const float* __restrict__ bhh1,   // [204]
                     const float* __restrict__ Wih2,   // [204, 51]
                     const float* __restrict__ Whh2,   // [204, 51]
                     const float* __restrict__ bih2,   // [204]
                     const float* __restrict__ bhh2,   // [204]
                     const float* __restrict__ Wl,     // [1, 51]
                     const float* __restrict__ blp,    // [1]
                     float* __restrict__ outp)         // [B, Ttot]
{
    const int tid = threadIdx.x;
    const int r   = tid >> 1;                 // gate-row candidate 0..255
    const int q   = tid & 1;                  // which half of the row
    const int j   = (r < G4) ? r : (G4 - 1);  // clamped row for weight loads
    const int b0  = blockIdx.x * NB;

    // hcat: [0..50]=h1, [51..55]=0, [56..106]=h2, [107..111]=0.
    // L1 dot = elems 0..55 (halves of 28); L2 dot = elems 0..111 (halves of 56).
    __shared__ float hcat[NB][112];
    __shared__ float gates[NB][G4];
    __shared__ float xnb[NB];

    if (tid < 112) { hcat[0][tid] = 0.f; hcat[1][tid] = 0.f; }

    // ---- per-thread HALF-row weights: 14+28 v2f = 84 floats (fits in VGPRs;
    // round-3 showed 156 floats/thread spills to scratch at any occupancy) ----
    v2f w1h[14];
#pragma unroll
    for (int p = 0; p < 14; ++p) {
        int i0 = q * 28 + 2 * p, i1 = i0 + 1;
        float a = (i0 < Hh) ? Whh1[j * Hh + i0] : 0.f;
        float b = (i1 < Hh) ? Whh1[j * Hh + i1] : 0.f;
        w1h[p].x = a; w1h[p].y = b;
    }
    v2f w2h[28];
#pragma unroll
    for (int p = 0; p < 28; ++p) {
        int i0 = q * 56 + 2 * p, i1 = i0 + 1;
        float a = (i0 < Hh) ? Wih2[j * Hh + i0]
                : ((i0 >= 56 && i0 < 56 + Hh) ? Whh2[j * Hh + i0 - 56] : 0.f);
        float b = (i1 < Hh) ? Wih2[j * Hh + i1]
                : ((i1 >= 56 && i1 < 56 + Hh) ? Whh2[j * Hh + i1 - 56] : 0.f);
        w2h[p].x = a; w2h[p].y = b;
    }
#pragma unroll
    for (int p = 0; p < 14; ++p) asm volatile("" : "+v"(w1h[p]));
#pragma unroll
    for (int p = 0; p < 28; ++p) asm volatile("" : "+v"(w2h[p]));

    const float b1j   = bih1[j] + bhh1[j];
    const float b2j   = bih2[j] + bhh2[j];
    const float wih1j = Wih1[j];

    // P2/P4 state role: waves 0 and 1 own batch 0 and 1, lanes jj<51.
    const int  sg     = tid >> 6;             // wave id
    const int  jj     = tid & 63;
    const bool strole = (tid < 128) && (jj < Hh);
    const float wlj   = strole ? Wl[jj] : 0.f;
    const float blv   = blp[0];
    float c1 = 0.f, c2 = 0.f;

    float xa = inp[(size_t)b0 * Tin];
    float xb = inp[(size_t)(b0 + 1) * Tin];
    const bool tg_row = (j >= 2 * Hh) && (j < 3 * Hh);   // tanh gate rows

    __syncthreads();

    for (int t = 0; t < Ttot; ++t) {
        float x0 = (t < Tin) ? xa : xnb[0];
        float x1 = (t < Tin) ? xb : xnb[1];
        float xan = 0.f, xbn = 0.f;
        if (t + 1 < Tin) {                   // prefetch next step's inputs
            xan = inp[(size_t)b0 * Tin + t + 1];
            xbn = inp[(size_t)(b0 + 1) * Tin + t + 1];
        }

        // ---- P1: layer-1 gates (half-dot + pair shuffle) ----
        {
            v2f aA0 = {q ? 0.f : __builtin_fmaf(x0, wih1j, b1j), 0.f};
            v2f aA1 = {0.f, 0.f};
            v2f aB0 = {q ? 0.f : __builtin_fmaf(x1, wih1j, b1j), 0.f};
            v2f aB1 = {0.f, 0.f};
            const float4* hA = (const float4*)&hcat[0][q * 28];
            const float4* hB = (const float4*)&hcat[1][q * 28];
#pragma unroll
            for (int p = 0; p < 7; ++p) {
                float4 ha = hA[p], hb = hB[p];
                v2f halo = {ha.x, ha.y}, hahi = {ha.z, ha.w};
                v2f hblo = {hb.x, hb.y}, hbhi = {hb.z, hb.w};
                aA0 = pk_fma(w1h[2 * p],     halo, aA0);
                aA1 = pk_fma(w1h[2 * p + 1], hahi, aA1);
                aB0 = pk_fma(w1h[2 * p],     hblo, aB0);
                aB1 = pk_fma(w1h[2 * p + 1], hbhi, aB1);
            }
            float pA = (aA0.x + aA1.x) + (aA0.y + aA1.y);
            float pB = (aB0.x + aB1.x) + (aB0.y + aB1.y);
            pA += __shfl_xor(pA, 1, 64);
            pB += __shfl_xor(pB, 1, 64);
            float a = q ? pB : pA;           // lane parity picks its batch
            float s = fast_sigmoid(tg_row ? 2.f * a : a);
            if (r < G4) gates[q][r] = tg_row ? (2.f * s - 1.f) : s;
        }
        __syncthreads();

        // ---- P2: layer-1 state ----
        if (strole) {
            float gi = gates[sg][jj],          gf = gates[sg][Hh + jj];
            float gg = gates[sg][2 * Hh + jj], go = gates[sg][3 * Hh + jj];
            c1 = __builtin_fmaf(gf, c1, gi * gg);
            hcat[sg][jj] = go * (2.f * fast_sigmoid(2.f * c1) - 1.f);
        }
        __syncthreads();

        // ---- P3: layer-2 gates (half-dot over [h1|pad|h2|pad]) ----
        {
            v2f aA0 = {q ? 0.f : b2j, 0.f}, aA1 = {0.f, 0.f};
            v2f aB0 = {q ? 0.f : b2j, 0.f}, aB1 = {0.f, 0.f};
            const float4* hA = (const float4*)&hcat[0][q * 56];
            const float4* hB = (const float4*)&hcat[1][q * 56];
#pragma unroll
            for (int p = 0; p < 14; ++p) {
                float4 ha = hA[p], hb = hB[p];
                v2f halo = {ha.x, ha.y}, hahi = {ha.z, ha.w};
                v2f hblo = {hb.x, hb.y}, hbhi = {hb.z, hb.w};
                aA0 = pk_fma(w2h[2 * p],     halo, aA0);
                aA1 = pk_fma(w2h[2 * p + 1], hahi, aA1);
                aB0 = pk_fma(w2h[2 * p],     hblo, aB0);
                aB1 = pk_fma(w2h[2 * p + 1], hbhi, aB1);
            }
            float pA = (aA0.x + aA1.x) + (aA0.y + aA1.y);
            float pB = (aB0.x + aB1.x) + (aB0.y + aB1.y);
            pA += __shfl_xor(pA, 1, 64);
            pB += __shfl_xor(pB, 1, 64);
            float a = q ? pB : pA;
            float s = fast_sigmoid(tg_row ? 2.f * a : a);
            if (r < G4) gates[q][r] = tg_row ? (2.f * s - 1.f) : s;
        }
        __syncthreads();

        // ---- P4: layer-2 state + linear output (per-wave reduce) ----
        float contrib = 0.f;
        if (strole) {
            float gi = gates[sg][jj],          gf = gates[sg][Hh + jj];
            float gg = gates[sg][2 * Hh + jj], go = gates[sg][3 * Hh + jj];
            c2 = __builtin_fmaf(gf, c2, gi * gg);
            float h2 = go * (2.f * fast_sigmoid(2.f * c2) - 1.f);
            hcat[sg][56 + jj] = h2;
            contrib = wlj * h2;
        }
        if (tid < 128) {                     // waves 0,1: one batch each
            float s = contrib;
#pragma unroll
            for (int m = 32; m >= 1; m >>= 1) s += __shfl_xor(s, m, 64);
            if (jj == 0) {
                float ov = s + blv;
                xnb[sg] = ov;                // feedback for future phase
                outp[(size_t)(b0 + sg) * Ttot + t] = ov;
            }
        }
        __syncthreads();
        xa = xan; xb = xbn;
    }
}

extern "C" void kernel_launch(void* const* d_in, const int* in_sizes, int n_in,
                              void* d_out, int out_size, void* d_ws, size_t ws_size,
                              hipStream_t stream) {
    (void)in_sizes; (void)n_in; (void)out_size; (void)d_ws; (void)ws_size;
    lstm_seq_kernel<<<dim3(Bsz / NB), dim3(512), 0, stream>>>(
        (const float*)d_in[0], (const float*)d_in[1],
        (const float*)d_in[2], (const float*)d_in[3],
        (const float*)d_in[4], (const float*)d_in[5],
        (const float*)d_in[6], (const float*)d_in[7],
        (const float*)d_in[8], (const float*)d_in[9],
        (const float*)d_in[10], (float*)d_out);
}